// Round 5
// baseline (264.253 us; speedup 1.0000x reference)
//
#include <hip/hip_runtime.h>
#include <math.h>

#define NB 16384
#define NTOK 128
#define NKEY 2662           // 22*11*11
#define NLOG 19
#define TB 8                // batches per workgroup in main kernel

typedef __attribute__((ext_vector_type(8))) short short8;
typedef __attribute__((ext_vector_type(4))) float floatx4;

struct Tok3 { int x, y, z; };

__device__ __constant__ float c_maxv[22] = {
    9.f, 1.f, 1.f, 10.f, 3.f, 254.f, 1.f, 1.f, 235.f, 8.f, 9.f, 250.f,
    29.f, 1.f, 1.f, 8.f, 1.f, 1.f, 6.f, 3.f, 1.f, 2.f};

__device__ __forceinline__ unsigned short f2bf(float f) {
    unsigned u = __float_as_uint(f);
    return (unsigned short)((u + 0x7FFFu + ((u >> 16) & 1u)) >> 16);  // RNE
}
__device__ __forceinline__ float tanh_fast(float x) {
    float e = __builtin_amdgcn_exp2f(x * 2.885390082f);   // 2*log2(e)
    return 1.f - 2.f * __builtin_amdgcn_rcpf(e + 1.f);
}

// ---------------------------------------------------------------------------
// Precompute A: W2Ft[uk][p] = sum_v fc1w[p][v]*w2[v][uk]  (576x128),
// encwT, beff/blog chain, Wlog, c1wb(bf16).  Grid = 107 WGs.
// ---------------------------------------------------------------------------
__global__ __launch_bounds__(256) void k_preA(
    const float* __restrict__ w1, const float* __restrict__ b1,
    const float* __restrict__ w2, const float* __restrict__ b2,
    const float* __restrict__ fc1w, const float* __restrict__ fc1b,
    const float* __restrict__ encw, const float* __restrict__ encb,
    const float* __restrict__ a1w, const float* __restrict__ a1b,
    const float* __restrict__ aemb,
    const float* __restrict__ h0w, const float* __restrict__ h0b,
    const float* __restrict__ h1w, const float* __restrict__ h1b,
    const float* __restrict__ c1w,
    float* __restrict__ W2Ft, float* __restrict__ encwT,
    float* __restrict__ beff, float* __restrict__ blog,
    float* __restrict__ Wlog, unsigned short* __restrict__ c1wb)
{
    __shared__ float sF[64 * 129];        // 33 KB (fc1w^T staged, pad 129)
    const int bid = blockIdx.x, t = threadIdx.x;

    if (bid < 72) {
        // ---- W2Ft: 8 uk rows per WG ----
        #pragma unroll
        for (int r = 0; r < 32; ++r) {    // stage fc1w^T: sF[v][p]
            int idx = t + 256 * r;        // 8192 = 128p x 64v
            int p_ = idx >> 6, v_ = idx & 63;
            sF[v_ * 129 + p_] = fc1w[idx];
        }
        __syncthreads();
        #pragma unroll
        for (int r = 0; r < 4; ++r) {
            int idx = t + 256 * r;        // 1024 = 8 ukl x 128 p
            int p = idx & 127;
            int uk = __builtin_amdgcn_readfirstlane(bid * 8 + (idx >> 7));
            float acc = 0.f;
            #pragma unroll 8
            for (int v = 0; v < 64; ++v)
                acc += sF[v * 129 + p] * w2[v * 576 + uk];
            W2Ft[uk * 128 + p] = acc;
        }
    } else if (bid == 72) {
        // ---- chain: h2b -> s_t -> beff; emb -> blog ----
        float* s_h2b = sF;          // [64]
        float* s_emb = sF + 64;     // [16]
        float* s_t   = sF + 80;     // [128]
        if (t < 64) {
            float s = b2[t];
            for (int u = 0; u < 64; ++u) {
                float ws = 0.f;
                for (int k = 0; k < 9; ++k) ws += w2[(t * 64 + u) * 9 + k];
                s += b1[u] * ws;
            }
            s_h2b[t] = s;
        } else if (t < 80) {
            int e = t - 64;
            float s = 0.f;
            for (int r = 0; r < 100; ++r) s += aemb[r * 16 + e];
            s_emb[e] = s * 0.01f;
        }
        __syncthreads();
        if (t < 128) {
            float s = fc1b[t];
            for (int v = 0; v < 64; ++v) s += fc1w[t * 64 + v] * s_h2b[v];
            s_t[t] = s;
        }
        __syncthreads();
        if (t < 128) {
            float s = encb[t];
            for (int p = 0; p < 128; ++p) s += encw[t * 128 + p] * s_t[p];
            beff[t] = s;
        } else if (t < 128 + NLOG) {
            int o = t - 128;
            float s = (o < 9) ? h0b[o] : h1b[o - 9];
            for (int a = 0; a < 512; ++a) {
                float hw = (o < 9) ? h0w[o * 528 + a] : h1w[(o - 9) * 528 + a];
                s += hw * a1b[a];
            }
            for (int e = 0; e < 16; ++e) {
                float hw = (o < 9) ? h0w[o * 528 + 512 + e] : h1w[(o - 9) * 528 + 512 + e];
                s += hw * s_emb[e];
            }
            blog[o] = s;
        }
    } else if (bid < 83) {
        // ---- Wlog[o][h] = sum_a headW[o][a] * actor1_w[a][h] ----
        int n = (bid - 73) * 256 + t;
        if (n < NLOG * 128) {
            int o = __builtin_amdgcn_readfirstlane(n >> 7);
            int h = n & 127;
            const float* hw = (o < 9) ? (h0w + o * 528) : (h1w + (o - 9) * 528);
            float acc = 0.f;
            #pragma unroll 8
            for (int a = 0; a < 512; ++a)
                acc += hw[a] * a1w[a * 128 + h];
            Wlog[n] = acc;
        }
    } else if (bid < 99) {
        // ---- c1wb bf16 convert, same [j][k] layout ----
        #pragma unroll
        for (int r = 0; r < 32; ++r) {
            int n = (bid - 83) * 8192 + t + 256 * r;   // 16*8192 = 131072
            c1wb[n] = f2bf(c1w[n]);
        }
    } else {
        // ---- encwT[p][h] = encw[h][p] ----
        #pragma unroll
        for (int r = 0; r < 8; ++r) {
            int idx = (bid - 99) * 2048 + t + 256 * r; // 8*2048 = 16384
            int h = idx >> 7, p = idx & 127;
            encwT[p * 128 + h] = encw[idx];
        }
    }
}

// ---------------------------------------------------------------------------
// Precompute B: Weff[key][h] (1/MAX folded). Grid = 1331 WGs, 2 keys each.
// A[key][p] = sum_{u,taps} w1[u,c,pos] * W2Ft[u*9+t][p]   (LDS)
// Weff[key][h] = sum_p encwT[p][h] * A[key][p]
// ---------------------------------------------------------------------------
__global__ __launch_bounds__(256) void k_preB(
    const float* __restrict__ W2Ft, const float* __restrict__ w1,
    const float* __restrict__ encwT, float* __restrict__ Weff)
{
    __shared__ float sA[2][128];
    const int t = threadIdx.x, bid = blockIdx.x;
    const int half = t >> 7, p = t & 127;
    const int key = __builtin_amdgcn_readfirstlane(bid * 2 + half);
    const int c = key / 121, rem = key % 121, X = rem / 11, Y = rem % 11;

    float acc = 0.f;
    for (int u = 0; u < 64; ++u) {
        const float* w1u = w1 + u * 550 + c * 25;
        #pragma unroll
        for (int i = 0; i < 3; ++i) {
            int xi = X - 3 * i;
            if (xi < 0 || xi > 4) continue;       // wave-uniform
            #pragma unroll
            for (int j = 0; j < 3; ++j) {
                int yj = Y - 3 * j;
                if (yj < 0 || yj > 4) continue;   // wave-uniform
                acc += w1u[xi * 5 + yj] * W2Ft[(u * 9 + i * 3 + j) * 128 + p];
            }
        }
    }
    sA[half][p] = acc / c_maxv[c];
    __syncthreads();

    float o = 0.f;
    #pragma unroll 8
    for (int p2 = 0; p2 < 128; ++p2)
        o += encwT[p2 * 128 + p] * sA[half][p2];
    Weff[key * 128 + p] = o;
}

// ---------------------------------------------------------------------------
// Main fused kernel. 256 threads, TB=8 batches/WG, grid = 2048 (8 WG/CU).
// ---------------------------------------------------------------------------
__global__ __launch_bounds__(256, 8) void k_main(
    const int* __restrict__ obs,
    const float* __restrict__ Weff, const float* __restrict__ beff,
    const unsigned short* __restrict__ c1wb, const float* __restrict__ c1b,
    const float* __restrict__ vw, const float* __restrict__ vb,
    const float* __restrict__ Wlog, const float* __restrict__ blog,
    float* __restrict__ out)
{
    __shared__ int            s_lst[TB * 32];      // 1 KB packed token list
    __shared__ float          s_hidden[TB * 128];  // 4 KB fp32 (for logits)
    __shared__ unsigned short s_hb[16 * 136];      // 4.25 KB bf16 (16 rows for MFMA)
    __shared__ int            s_cnt[TB];
    __shared__ float          s_val[64];

    const int tid = threadIdx.x, bid = blockIdx.x;
    const int b0 = bid * TB;

    if (tid < TB) s_cnt[tid] = 0;
    for (int i = tid; i < 8 * 136; i += 256) s_hb[8 * 136 + i] = 0;  // rows 8..15
    __syncthreads();

    // ---- Phase A: decode + append valid tokens (pack m<<20|val<<12|key) ----
    {
        const Tok3* obs3 = (const Tok3*)obs;
        const int gtok0 = b0 * NTOK;
        #pragma unroll
        for (int k = 0; k < TB * NTOK / 256; ++k) {
            int tt = tid + 256 * k;                // tt = bb*128 + m
            Tok3 o = obs3[gtok0 + tt];
            int o0 = (o.x == 255) ? 0 : o.x;       // per-component 255 masking
            int o1 = (o.y == 255) ? 0 : o.y;
            int o2 = (o.z == 255) ? 0 : o.z;
            int x = (o0 >> 4) & 15, y = o0 & 15;
            if (x < 11 && y < 11 && o1 < 22) {
                int bb = tt >> 7, m = tt & 127;
                int pos = atomicAdd(&s_cnt[bb], 1);
                if (pos < 32)
                    s_lst[bb * 32 + pos] = (m << 20) | (o2 << 12) | (o1 * 121 + x * 11 + y);
            }
        }
    }
    __syncthreads();

    // ---- Phase A2: last-write-wins dedupe on the tiny list ----
    {
        int bb = tid >> 5, e = tid & 31;
        int n = s_cnt[bb]; if (n > 32) n = 32;
        if (e < n) {
            int p = s_lst[bb * 32 + e];
            bool dead = false;
            for (int i = 0; i < n; ++i) {
                int q = s_lst[bb * 32 + i];
                dead |= (((q ^ p) & 0xFFF) == 0) && (q > p);
            }
            if (dead) s_lst[bb * 32 + e] = p & ~0x000FF000;  // val := 0
        }
    }
    __syncthreads();

    // ---- Phase B: hidden[b][h] = b_eff[h] + sum val * Weff[key][h] ----
    {
        int h = tid & 127, bg = tid >> 7;
        for (int bb = bg; bb < TB; bb += 2) {
            float acc = beff[h];
            int n = s_cnt[bb]; if (n > 32) n = 32;
            for (int i = 0; i < n; ++i) {
                int p = s_lst[bb * 32 + i];
                acc += (float)((p >> 12) & 0xFF) * Weff[(p & 0xFFF) * 128 + h];
            }
            s_hidden[bb * 128 + h] = acc;
            s_hb[bb * 136 + h] = f2bf(acc);
        }
    }
    __syncthreads();

    // ---- Phase C: value = sum_j tanh(hidden @ c1w.T + b)_j * vw_j (MFMA) ----
    {
        const int lane = tid & 63, w = tid >> 6;
        const int lm = lane & 15, quad = lane >> 4;
        short8 af[4];
        #pragma unroll
        for (int kk = 0; kk < 4; ++kk)
            af[kk] = *(const short8*)&s_hb[lm * 136 + kk * 32 + quad * 8];

        float vpart[4] = {0.f, 0.f, 0.f, 0.f};
        for (int nt = 0; nt < 16; ++nt) {
            int j = w * 256 + nt * 16 + lm;
            floatx4 acc = {0.f, 0.f, 0.f, 0.f};
            #pragma unroll
            for (int kk = 0; kk < 4; ++kk) {
                short8 bf = *(const short8*)&c1wb[j * 128 + kk * 32 + quad * 8];
                acc = __builtin_amdgcn_mfma_f32_16x16x32_bf16(af[kk], bf, acc, 0, 0, 0);
            }
            float bj = c1b[j], wj = vw[j];
            #pragma unroll
            for (int r = 0; r < 4; ++r)
                vpart[r] += tanh_fast(acc[r] + bj) * wj;
        }
        #pragma unroll
        for (int off = 1; off <= 8; off <<= 1)
            #pragma unroll
            for (int r = 0; r < 4; ++r)
                vpart[r] += __shfl_xor(vpart[r], off, 64);
        if (lm == 0) {
            #pragma unroll
            for (int r = 0; r < 4; ++r)
                s_val[w * 16 + quad * 4 + r] = vpart[r];
        }
    }
    __syncthreads();
    if (tid < TB) {
        float v = s_val[tid] + s_val[16 + tid] + s_val[32 + tid] + s_val[48 + tid];
        out[NB * NLOG + b0 + tid] = v + vb[0];
    }

    // ---- Phase D: logits[b][o] = blog[o] + hidden[b]·Wlog[o]  (fp32) ----
    {
        const float4* s_h4 = (const float4*)s_hidden;
        const float4* wl4  = (const float4*)Wlog;
        int bl = tid >> 5, o = tid & 31;
        if (o < NLOG) {
            float acc = blog[o];
            #pragma unroll
            for (int hq = 0; hq < 32; ++hq) {
                float4 hv = s_h4[bl * 32 + hq];
                float4 wl = wl4[o * 32 + hq];
                acc += wl.x * hv.x + wl.y * hv.y + wl.z * hv.z + wl.w * hv.w;
            }
            out[(b0 + bl) * NLOG + o] = acc;
        }
    }
}

// ---------------------------------------------------------------------------
extern "C" void kernel_launch(void* const* d_in, const int* in_sizes, int n_in,
                              void* d_out, int out_size, void* d_ws, size_t ws_size,
                              hipStream_t stream)
{
    const int*   obs  = (const int*)  d_in[0];
    const float* w1   = (const float*)d_in[1];
    const float* b1   = (const float*)d_in[2];
    const float* w2   = (const float*)d_in[3];
    const float* b2   = (const float*)d_in[4];
    const float* fc1w = (const float*)d_in[5];
    const float* fc1b = (const float*)d_in[6];
    const float* encw = (const float*)d_in[7];
    const float* encb = (const float*)d_in[8];
    const float* c1w  = (const float*)d_in[9];
    const float* c1b  = (const float*)d_in[10];
    const float* vw   = (const float*)d_in[11];
    const float* vb   = (const float*)d_in[12];
    const float* a1w  = (const float*)d_in[13];
    const float* a1b  = (const float*)d_in[14];
    const float* aemb = (const float*)d_in[15];
    const float* h0w  = (const float*)d_in[16];
    const float* h0b  = (const float*)d_in[17];
    const float* h1w  = (const float*)d_in[18];
    const float* h1b  = (const float*)d_in[19];

    float* W     = (float*)d_ws;
    float* W2Ft  = W;                 // 73728  (576 x 128)
    float* encwT = W + 73728;         // 16384
    float* beff  = W + 90112;         // 128
    float* blog  = W + 90240;         // 32
    float* Wlog  = W + 90272;         // 2432
    float* Weff  = W + 92704;         // 340736
    unsigned short* c1wb = (unsigned short*)(W + 433440);  // 131072 ushort

    hipLaunchKernelGGL(k_preA, dim3(107), dim3(256), 0, stream,
                       w1, b1, w2, b2, fc1w, fc1b, encw, encb, a1w, a1b, aemb,
                       h0w, h0b, h1w, h1b, c1w,
                       W2Ft, encwT, beff, blog, Wlog, c1wb);
    hipLaunchKernelGGL(k_preB, dim3(1331), dim3(256), 0, stream,
                       W2Ft, w1, encwT, Weff);
    hipLaunchKernelGGL(k_main, dim3(NB / TB), dim3(256), 0, stream,
                       obs, Weff, beff, c1wb, c1b, vw, vb, Wlog, blog,
                       (float*)d_out);
}